// Round 10
// baseline (31.240 us; speedup 1.0000x reference)
//
#include <hip/hip_runtime.h>

// out[b,k] = tanh( sum_{m in segment k} x[b,m] * w[m] ),  seg_ids sorted.
//
// R10: persistent software-pipelined waves + LDS slab + carry fixup.
//  - 2048 persistent waves; wave owns ONE 1024-float window (w,ids in regs,
//    loaded once) and loops over ITERS=4 batch-pairs (rows bp, bp+128).
//  - Register double-buffer: issue next pair's 8 float4 x-loads, compute
//    current pair, then rotate (rotation forces the vmcnt wait AFTER compute
//    -> every compute phase overlaps the next loads; sustained issue duty,
//    the property every R1-R9 one-shot-wave kernel lacked).
//  - Flush: STEP run-accumulate -> per-wave-private LDS slab (ds_add_f32),
//    intra-wave sync via inline lgkmcnt+sched_barrier (rule 18); interiors
//    get tanh stores, window-edge ids go to carry buffer; fixup merges.
// R9 lesson: burst-loading one-shot waves still ~3 TB/s; this tests
// sustained per-wave pipelining as the last structural lever.

#define TPB   256
#define WIN   1024            // floats per window
#define EPL   16              // elems per lane
#define SLOTS 192             // id-span capacity per row (span ~64±16)
#define ITERS 4               // batch-pairs per wave

__global__ __launch_bounds__(TPB) void zero_out_k(float* __restrict__ out, int n4) {
    int i = blockIdx.x * blockDim.x + threadIdx.x;
    if (i < n4) reinterpret_cast<float4*>(out)[i] = make_float4(0.f, 0.f, 0.f, 0.f);
}

__global__ __launch_bounds__(TPB) void seg_persist(
        const float* __restrict__ x,
        const float* __restrict__ w,
        const int*   __restrict__ ids,
        float* __restrict__ out,
        float* __restrict__ carry,
        int M, int K, int NW, int B) {
    __shared__ float slab[TPB / 64][2][SLOTS];

    const int ln  = threadIdx.x & 63;
    const int wv  = threadIdx.x >> 6;
    const int wid = blockIdx.x * (TPB / 64) + wv;     // 0..2047
    const int win = wid % NW;                          // window (fixed per wave)
    const int grp = wid / NW;                          // 0..31
    const int bp0 = grp * ITERS;                       // batch-pair group base
    const size_t mbase = (size_t)win * WIN + (size_t)ln * EPL;
    const int halfB = B / 2;                           // 128

    // ---- per-wave constants: ids + w, loaded once ----
    const int4*   id4 = reinterpret_cast<const int4*>(ids + mbase);
    const float4* w4  = reinterpret_cast<const float4*>(w + mbase);
    int4   i0 = id4[0], i1 = id4[1], i2 = id4[2], i3 = id4[3];
    float4 q0 = w4[0],  q1 = w4[1],  q2 = w4[2],  q3 = w4[3];

    const int firstId = __shfl(i0.x, 0);               // ids[win*WIN]
    const int lastId  = __shfl(i3.w, 63);              // ids[win*WIN+WIN-1]
    const int span    = min(lastId - firstId + 1, SLOTS);

    float* __restrict__ sA = slab[wv][0];
    float* __restrict__ sB = slab[wv][1];

    // ---- prologue: load first pair ----
    float4 aC[4], cC[4], aN[4], cN[4];
    {
        const float4* xa4 = reinterpret_cast<const float4*>(x + (size_t)bp0 * M + mbase);
        const float4* xb4 = reinterpret_cast<const float4*>(x + (size_t)(bp0 + halfB) * M + mbase);
        aC[0] = xa4[0]; aC[1] = xa4[1]; aC[2] = xa4[2]; aC[3] = xa4[3];
        cC[0] = xb4[0]; cC[1] = xb4[1]; cC[2] = xb4[2]; cC[3] = xb4[3];
    }

    #pragma unroll
    for (int it = 0; it < ITERS; ++it) {
        const int bp  = bp0 + it;
        const int bpn = bp0 + ((it + 1 < ITERS) ? (it + 1) : it);
        // ---- issue next pair's loads (consumed next iteration) ----
        {
            const float4* xa4 = reinterpret_cast<const float4*>(x + (size_t)bpn * M + mbase);
            const float4* xb4 = reinterpret_cast<const float4*>(x + (size_t)(bpn + halfB) * M + mbase);
            aN[0] = xa4[0]; aN[1] = xa4[1]; aN[2] = xa4[2]; aN[3] = xa4[3];
            cN[0] = xb4[0]; cN[1] = xb4[1]; cN[2] = xb4[2]; cN[3] = xb4[3];
        }
        // ---- zero my private slab region ----
        #pragma unroll
        for (int i = ln; i < 2 * SLOTS; i += 64) (&sA[0])[i] = 0.f;  // sA,sB contiguous
        asm volatile("s_waitcnt lgkmcnt(0)" ::: "memory");
        __builtin_amdgcn_sched_barrier(0);

        // ---- run-accumulate current pair into slab ----
        float accA = 0.f, accB = 0.f;
        int prev = i0.x;
        #define STEP(idv, xav, xbv, wvv)                               \
            if ((idv) != prev) {                                       \
                int s = min(prev - firstId, SLOTS - 1);                \
                atomicAdd(&sA[s], accA);                               \
                atomicAdd(&sB[s], accB);                               \
                accA = 0.f; accB = 0.f; prev = (idv);                  \
            }                                                          \
            accA = fmaf((xav), (wvv), accA);                           \
            accB = fmaf((xbv), (wvv), accB);

        STEP(i0.x, aC[0].x, cC[0].x, q0.x)  STEP(i0.y, aC[0].y, cC[0].y, q0.y)
        STEP(i0.z, aC[0].z, cC[0].z, q0.z)  STEP(i0.w, aC[0].w, cC[0].w, q0.w)
        STEP(i1.x, aC[1].x, cC[1].x, q1.x)  STEP(i1.y, aC[1].y, cC[1].y, q1.y)
        STEP(i1.z, aC[1].z, cC[1].z, q1.z)  STEP(i1.w, aC[1].w, cC[1].w, q1.w)
        STEP(i2.x, aC[2].x, cC[2].x, q2.x)  STEP(i2.y, aC[2].y, cC[2].y, q2.y)
        STEP(i2.z, aC[2].z, cC[2].z, q2.z)  STEP(i2.w, aC[2].w, cC[2].w, q2.w)
        STEP(i3.x, aC[3].x, cC[3].x, q3.x)  STEP(i3.y, aC[3].y, cC[3].y, q3.y)
        STEP(i3.z, aC[3].z, cC[3].z, q3.z)  STEP(i3.w, aC[3].w, cC[3].w, q3.w)
        #undef STEP
        {
            int s = min(prev - firstId, SLOTS - 1);
            atomicAdd(&sA[s], accA);
            atomicAdd(&sB[s], accB);
        }
        asm volatile("s_waitcnt lgkmcnt(0)" ::: "memory");
        __builtin_amdgcn_sched_barrier(0);

        // ---- writeback: interiors -> tanh store; edges -> carry ----
        for (int i = ln; i < 2 * span; i += 64) {
            int rr  = (i >= span) ? 1 : 0;
            int s   = i - rr * span;
            int id  = firstId + s;
            int row = rr ? (bp + halfB) : bp;
            float v = slab[wv][rr][s];
            if (s == 0)
                carry[((size_t)row * NW + win) * 2 + 0] = v;
            else if (id == lastId)
                carry[((size_t)row * NW + win) * 2 + 1] = v;
            else
                out[(size_t)row * K + id] = tanhf(v);
        }
        asm volatile("s_waitcnt lgkmcnt(0)" ::: "memory");
        __builtin_amdgcn_sched_barrier(0);

        // ---- rotate buffers (forces vmcnt wait AFTER compute) ----
        #pragma unroll
        for (int j = 0; j < 4; ++j) { aC[j] = aN[j]; cC[j] = cN[j]; }
    }
}

__global__ __launch_bounds__(TPB) void seg_fixup(
        const int*   __restrict__ ids,
        const float* __restrict__ carry,
        float* __restrict__ out,
        int K, int NW, int B) {
    int t = blockIdx.x * blockDim.x + threadIdx.x;
    if (t >= B * NW) return;
    int row = t / NW;
    int win = t - row * NW;

    int firstId = ids[win * WIN];
    int lastId  = ids[win * WIN + WIN - 1];
    float cF = carry[((size_t)row * NW + win) * 2 + 0];
    float cL = carry[((size_t)row * NW + win) * 2 + 1];

    int prevLast = (win > 0) ? ids[win * WIN - 1] : -1;
    if (prevLast != firstId)
        out[(size_t)row * K + firstId] = tanhf(cF);

    float tot = cL;
    if (win + 1 < NW) {
        int nextFirst = ids[(win + 1) * WIN];
        if (nextFirst == lastId)
            tot += carry[((size_t)row * NW + win + 1) * 2 + 0];
    }
    out[(size_t)row * K + lastId] = tanhf(tot);
}

extern "C" void kernel_launch(void* const* d_in, const int* in_sizes, int n_in,
                              void* d_out, int out_size, void* d_ws, size_t ws_size,
                              hipStream_t stream) {
    const float* x       = (const float*)d_in[0];
    const float* w       = (const float*)d_in[1];
    const int*   seg_ids = (const int*)d_in[2];
    float* out = (float*)d_out;

    const int M = in_sizes[1];           // 65536
    const int B = in_sizes[0] / M;       // 256
    const int K = out_size / B;          // 4096
    const int NW = M / WIN;              // 64

    float* carry = (float*)d_ws;         // B*NW*2 floats = 128 KB

    const int n4 = out_size / 4;
    zero_out_k<<<(n4 + TPB - 1) / TPB, TPB, 0, stream>>>(out, n4);

    // waves = NW * (B/2/ITERS) * ... = 64 windows * 32 groups = 2048 waves
    const int nwaves = NW * ((B / 2) / ITERS);         // 2048
    const int nblk   = nwaves / (TPB / 64);            // 512 blocks
    seg_persist<<<nblk, TPB, 0, stream>>>(x, w, seg_ids, out, carry, M, K, NW, B);

    const int nfix = B * NW;             // 16384
    seg_fixup<<<(nfix + TPB - 1) / TPB, TPB, 0, stream>>>(seg_ids, carry, out, K, NW, B);
}